// Round 6
// baseline (356.106 us; speedup 1.0000x reference)
//
#include <hip/hip_runtime.h>

typedef unsigned short u16;
typedef unsigned int u32;
typedef unsigned long long u64;
typedef _Float16 f16x8 __attribute__((ext_vector_type(8)));
typedef float f32x4 __attribute__((ext_vector_type(4)));

__device__ __forceinline__ u16 f2h(float f) {
    _Float16 h = (_Float16)f;
    return __builtin_bit_cast(u16, h);
}

// ---------------- conv1d(256->128,k=3,pad=1) + ReLU -> hT[b][t][c] fp32 ----------------
__global__ void conv_kernel(const float* __restrict__ x, const float* __restrict__ w,
                            const float* __restrict__ bias, float* __restrict__ hT) {
    int t = blockIdx.x, b = blockIdx.y, co = threadIdx.x;  // 128 threads
    float acc = bias[co];
    const float* xb = x + b * 256 * 128;
    const float* wr = w + co * 768;
    for (int ci = 0; ci < 256; ++ci) {
        float x0 = (t >= 1)   ? xb[ci * 128 + t - 1] : 0.f;
        float x1 =              xb[ci * 128 + t];
        float x2 = (t < 127) ? xb[ci * 128 + t + 1] : 0.f;
        acc += x0 * wr[ci * 3 + 0] + x1 * wr[ci * 3 + 1] + x2 * wr[ci * 3 + 2];
    }
    hT[b * 16384 + t * 128 + co] = fmaxf(acc, 0.f);
}

// ---------------- prep: blocks 0..255 cvt W2 -> fp16; block 256: tab + c0 ----------------
__global__ void prep_kernel(const float* __restrict__ w2d, const float* __restrict__ b3,
                            const float* __restrict__ b2, int* __restrict__ tab,
                            u16* __restrict__ W2h, float* __restrict__ c0) {
    if (blockIdx.x < 256) {
        int i = blockIdx.x * 256 + threadIdx.x;
        W2h[i] = f2h(w2d[i]);
        return;
    }
    for (int cell = threadIdx.x; cell < 8256; cell += 256) {
        int off = 0, d = 0;
        while (d < 128) { int w = 128 - d; if (cell < off + w) break; off += w; ++d; }
        tab[cell] = (d << 8) | (cell - off);
    }
    if (threadIdx.x < 128) {
        int o2 = threadIdx.x;
        float s = b2[o2];
        for (int o = 0; o < 512; ++o) s += w2d[o2 * 512 + o] * fmaxf(b3[o], 0.f);
        c0[o2] = fmaxf(s, 0.f);
    }
}

// ---------------- fp32 -> fp16 convert (W3) ----------------
__global__ void cvt_kernel(const float* __restrict__ src, u16* __restrict__ dst, int n) {
    int i = blockIdx.x * blockDim.x + threadIdx.x;
    if (i < n) dst[i] = f2h(src[i]);
}

// ---------------- fill invalid cells with c0 ----------------
__global__ void fill_kernel(const float* __restrict__ c0, float* __restrict__ out) {
    int d = blockIdx.x, b = blockIdx.y;
    if (d == 0) return;
    int cnt = d, total = 128 * cnt;
    for (int idx = threadIdx.x; idx < total; idx += blockDim.x) {
        int o2 = idx / cnt, m = 128 - cnt + (idx % cnt);
        out[((size_t)b << 21) + ((size_t)o2 << 14) + (d << 7) + m] = c0[o2];
    }
}

// ---------------- build MBt[(b,cell)][(c,n)] fp16 from hT + closed-form taps ----------------
// Tap positions must match numpy's double arithmetic bit-for-bit (cliff at s==-1.0):
// mul-then-add with contract(off), never fma.
__global__ __launch_bounds__(256) void mb_build(const float* __restrict__ hT,
                                                const int* __restrict__ tab,
                                                u16* __restrict__ MBt) {
#pragma clang fp contract(off)
    __shared__ float hs[128][129];
    int c0g = blockIdx.x * 8;
    int b = (c0g >= 8256) ? 1 : 0;
    const float* hb = hT + b * 16384;
    for (int idx = threadIdx.x; idx < 16384; idx += 256)
        hs[idx >> 7][idx & 127] = hb[idx];
    __syncthreads();
    int n = threadIdx.x & 31, cb = threadIdx.x >> 5;
    for (int cc = 0; cc < 8; ++cc) {
        int colg = c0g + cc;
        int cell = colg - b * 8256;
        int dm = tab[cell];
        int d = dm >> 8, m = dm & 255;
        double xm = m - (d + 1) * 0.5;
        double step = (2 * d + 1) / 95.0;
        float tw[6]; int tt[6];
#pragma unroll
        for (int j = 0; j < 3; ++j) {
            double p = step * (double)(3 * n + j);
            double s = xm + p;
            double tr = trunc(s);
            double dec = s - tr;
            int dn = (int)tr;
            int up = (int)ceil(s);
            bool vdn = (dn >= 0 && dn <= 127);
            bool vup = (up >= 0 && up <= 127);
            tt[2 * j]     = vdn ? dn : 0;
            tw[2 * j]     = vdn ? (float)((1.0 - dec) * (1.0 / 3.0)) : 0.f;
            tt[2 * j + 1] = vup ? up : 0;
            tw[2 * j + 1] = vup ? (float)(dec * (1.0 / 3.0)) : 0.f;
        }
        u16 vals[16];
#pragma unroll
        for (int k = 0; k < 16; ++k) {
            int c = cb + (k << 3);
            float v = 0.f;
#pragma unroll
            for (int i = 0; i < 6; ++i) v = fmaf(tw[i], hs[tt[i]][c], v);
            vals[k] = f2h(v);
        }
        size_t base = (size_t)colg * 4096;
#pragma unroll
        for (int k = 0; k < 16; ++k)
            MBt[base + threadIdx.x + (k << 8)] = vals[k];
    }
}

// ---------------- fused mega-GEMM v3 ----------------
// Grid = 130 blocks (65 panels x 2 batches), 512 thr (8 waves). BM=512, BN=128, BK=64.
// Only B (MBt panel) staged in LDS (dbuf 2x16KB, XOR-swizzled). A (W3h, 4MB) is read
// directly from global per-fragment: no intra-block A reuse exists, and W3h is L2-resident
// per XCD, so LDS staging of A was pure overhead (R5: 72KB/iter feed-bound at 56B/cyc).
// Wave tile 64m x 128n; acc 4x8 f32x4 = 128 VGPR.
__global__ __launch_bounds__(512, 2) void mega_kernel(
        const u16* __restrict__ W3h, const u16* __restrict__ MBt,
        const u16* __restrict__ W2h,
        const float* __restrict__ b3, const float* __restrict__ b2,
        const int* __restrict__ tab, float* __restrict__ out) {
    __shared__ alignas(16) char lds[133120];   // K-loop: B dbuf 2x16KB; epilogue: m3s 130KB

    const int tid = threadIdx.x;
    const int lane = tid & 63, wv = tid >> 6;      // wave 0..7 = M-group
    const int fr = lane & 15, fq = lane >> 4;
    const int swz = (fr & 7) << 4;

    const int p = blockIdx.x;
    const int b = (p >= 65) ? 1 : 0;
    const int pi = p - 65 * b;
    const int cell0 = pi * 128;
    const int cn = (pi == 64) ? 64 : 128;          // last panel has 64 cells
    const size_t brow0 = (size_t)b * 8256 + cell0;

    f32x4 acc[4][8] = {};

    auto stage = [&](int buf, int kt) {
        char* B = lds + buf * 16384;
#pragma unroll
        for (int i = 0; i < 2; ++i) {
            int off = i * 8192 + tid * 16;          // 16KB tile: [128 rows][128 B]
            int row = off >> 7, colb = off & 127;
            int r2 = row < cn ? row : 0;            // clamp partial panel (no OOB)
            int scol = colb ^ ((row & 7) << 4);     // pre-swizzled source
            const u16* gb = MBt + (brow0 + r2) * 4096 + kt + (scol >> 1);
            __builtin_amdgcn_global_load_lds(
                (const __attribute__((address_space(1))) void*)gb,
                (__attribute__((address_space(3))) void*)(B + off), 16, 0, 0);
        }
    };

    stage(0, 0);
    __syncthreads();
    for (int t = 0; t < 64; ++t) {
        int cur = t & 1;
        if (t < 63) stage(cur ^ 1, (t + 1) << 6);
        const char* B = lds + cur * 16384;
#pragma unroll
        for (int kk = 0; kk < 2; ++kk) {
            const int kofs = (t << 6) + kk * 32 + fq * 8;
            f16x8 af[4], bfr[8];
#pragma unroll
            for (int mf = 0; mf < 4; ++mf)
                af[mf] = *(const f16x8*)(W3h + (size_t)(wv * 64 + mf * 16 + fr) * 4096 + kofs);
            const int kb = (kk * 64 + (fq << 4)) ^ swz;
#pragma unroll
            for (int nf = 0; nf < 8; ++nf)
                bfr[nf] = *(const f16x8*)(B + (nf * 16 + fr) * 128 + kb);
#pragma unroll
            for (int mf = 0; mf < 4; ++mf)
#pragma unroll
                for (int nf = 0; nf < 8; ++nf)
                    acc[mf][nf] = __builtin_amdgcn_mfma_f32_16x16x32_f16(
                        af[mf], bfr[nf], acc[mf][nf], 0, 0, 0);
        }
        __syncthreads();
    }

    // ---- epilogue 1: m3s[cell][o], pitch 520 fp16 (1040B stride -> 2-way banks, free)
    u16* m3s = (u16*)lds;
#pragma unroll
    for (int mf = 0; mf < 4; ++mf) {
        int ob = wv * 64 + mf * 16 + (fq << 2);
#pragma unroll
        for (int nf = 0; nf < 8; ++nf) {
            int cell = nf * 16 + fr;
            f32x4 v = acc[mf][nf];
            u64 pw = 0;
#pragma unroll
            for (int r = 0; r < 4; ++r) {
                float z = fmaxf(v[r] + b3[ob + r], 0.f);
                pw |= (u64)f2h(z) << (16 * r);
            }
            *(u64*)(m3s + cell * 520 + ob) = pw;
        }
    }
    __syncthreads();

    // ---- epilogue 2: out = relu(W2 . m3 + b2); wave wv owns o2 rows wv*16..wv*16+15
    f32x4 acc2[8] = {};
#pragma unroll
    for (int kk = 0; kk < 16; ++kk) {
        f16x8 a2 = *(const f16x8*)(W2h + (wv * 16 + fr) * 512 + kk * 32 + (fq << 3));
#pragma unroll
        for (int nf = 0; nf < 8; ++nf) {
            f16x8 bfr = *(const f16x8*)(m3s + (nf * 16 + fr) * 520 + kk * 32 + (fq << 3));
            acc2[nf] = __builtin_amdgcn_mfma_f32_16x16x32_f16(a2, bfr, acc2[nf], 0, 0, 0);
        }
    }
#pragma unroll
    for (int nf = 0; nf < 8; ++nf) {
        int cl = nf * 16 + fr;
        if (cl < cn) {
            int dm = tab[cell0 + cl];
            size_t base = ((size_t)b << 21) + (size_t)((dm >> 8) << 7) + (dm & 255);
            f32x4 v = acc2[nf];
#pragma unroll
            for (int r = 0; r < 4; ++r) {
                int o2 = wv * 16 + (fq << 2) + r;
                float z = fmaxf(v[r] + b2[o2], 0.f);
                out[base + ((size_t)o2 << 14)] = z;
            }
        }
    }
}

// ws layout (bytes):
//   0        hT      fp32 [2][128][128]            131072
//   131072   W3h     fp16 [512][4096]              4194304
//   4325376  W2h     fp16 [128][512]               131072
//   4456448  c0      fp32 [128]                    512
//   4456960  tab     int  [8256] (alloc 16512)     66048
//   21562368 MBt     fp16 [16512][4096]            135266304
extern "C" void kernel_launch(void* const* d_in, const int* in_sizes, int n_in,
                              void* d_out, int out_size, void* d_ws, size_t ws_size,
                              hipStream_t stream) {
    const float* x     = (const float*)d_in[0];
    const float* w_red = (const float*)d_in[1];
    const float* b_red = (const float*)d_in[2];
    const float* w3d   = (const float*)d_in[3];
    const float* b3d   = (const float*)d_in[4];
    const float* w2d   = (const float*)d_in[5];
    const float* b2d   = (const float*)d_in[6];
    float* out = (float*)d_out;

    char* ws = (char*)d_ws;
    float* hT  = (float*)(ws + 0);
    u16*   W3h = (u16*)(ws + 131072);
    u16*   W2h = (u16*)(ws + 4325376);
    float* c0  = (float*)(ws + 4456448);
    int*   tab = (int*)(ws + 4456960);
    u16*   MBt = (u16*)(ws + 21562368);

    conv_kernel<<<dim3(128, 2), 128, 0, stream>>>(x, w_red, b_red, hT);
    prep_kernel<<<257, 256, 0, stream>>>(w2d, b3d, b2d, tab, W2h, c0);
    cvt_kernel<<<8192, 256, 0, stream>>>(w3d, W3h, 2097152);
    mb_build<<<2064, 256, 0, stream>>>(hT, tab, MBt);
    mega_kernel<<<130, 512, 0, stream>>>(W3h, MBt, W2h, b3d, b2d, tab, out);
    fill_kernel<<<dim3(128, 2), 256, 0, stream>>>(c0, out);
}

// Round 7
// 289.694 us; speedup vs baseline: 1.2292x; 1.2292x over previous
//
#include <hip/hip_runtime.h>

typedef unsigned short u16;
typedef unsigned int u32;
typedef unsigned long long u64;
typedef _Float16 f16x8 __attribute__((ext_vector_type(8)));
typedef float f32x4 __attribute__((ext_vector_type(4)));

__device__ __forceinline__ u16 f2h(float f) {
    _Float16 h = (_Float16)f;
    return __builtin_bit_cast(u16, h);
}

// ---------------- conv1d(256->128,k=3,pad=1)+ReLU -> hT[b][t][c] fp32 ----------------
// thread = t (coalesced x reads); block = (co, b) (w reads wave-uniform -> scalar loads)
__global__ void conv_kernel(const float* __restrict__ x, const float* __restrict__ w,
                            const float* __restrict__ bias, float* __restrict__ hT) {
    int co = blockIdx.x, b = blockIdx.y, t = threadIdx.x;  // 128 threads
    float acc = bias[co];
    const float* xb = x + b * 256 * 128;
    const float* wr = w + co * 768;
    for (int ci = 0; ci < 256; ++ci) {
        float w0 = wr[ci * 3 + 0], w1 = wr[ci * 3 + 1], w2 = wr[ci * 3 + 2];
        float x1 = xb[ci * 128 + t];
        float x0 = (t >= 1)   ? xb[ci * 128 + t - 1] : 0.f;
        float x2 = (t < 127) ? xb[ci * 128 + t + 1] : 0.f;
        acc += x0 * w0 + x1 * w1 + x2 * w2;
    }
    hT[b * 16384 + t * 128 + co] = fmaxf(acc, 0.f);
}

// ---------------- prep: 0..255 cvt W2; 256: tab; 257: c0 (parallel reduce) ----------------
__global__ void prep_kernel(const float* __restrict__ w2d, const float* __restrict__ b3,
                            const float* __restrict__ b2, int* __restrict__ tab,
                            u16* __restrict__ W2h, float* __restrict__ c0) {
    if (blockIdx.x < 256) {
        int i = blockIdx.x * 256 + threadIdx.x;
        W2h[i] = f2h(w2d[i]);
        return;
    }
    if (blockIdx.x == 256) {
        for (int cell = threadIdx.x; cell < 8256; cell += 256) {
            int off = 0, d = 0;
            while (d < 128) { int w = 128 - d; if (cell < off + w) break; off += w; ++d; }
            tab[cell] = (d << 8) | (cell - off);
        }
        return;
    }
    // c0: 256 threads, 2 per o2 (each sums 256 terms), pair-combine via shfl
    int o2 = threadIdx.x >> 1, half = threadIdx.x & 1;
    float s = 0.f;
    const float* row = w2d + o2 * 512 + half * 256;
    for (int o = 0; o < 256; ++o) s += row[o] * fmaxf(b3[half * 256 + o], 0.f);
    s += __shfl_xor(s, 1);
    if (half == 0) c0[o2] = fmaxf(s + b2[o2], 0.f);
}

// ---------------- fp32 -> fp16 convert (W3) ----------------
__global__ void cvt_kernel(const float* __restrict__ src, u16* __restrict__ dst, int n) {
    int i = blockIdx.x * blockDim.x + threadIdx.x;
    if (i < n) dst[i] = f2h(src[i]);
}

// ---------------- fill invalid cells with c0 ----------------
__global__ void fill_kernel(const float* __restrict__ c0, float* __restrict__ out) {
    int d = blockIdx.x, b = blockIdx.y;
    if (d == 0) return;
    int cnt = d, total = 128 * cnt;
    for (int idx = threadIdx.x; idx < total; idx += blockDim.x) {
        int o2 = idx / cnt, m = 128 - cnt + (idx % cnt);
        out[((size_t)b << 21) + ((size_t)o2 << 14) + (d << 7) + m] = c0[o2];
    }
}

// ---------------- build MBt[(b,cell)][(c,n)] fp16 (bit-exact taps; contract off) --------
__global__ __launch_bounds__(256) void mb_build(const float* __restrict__ hT,
                                                const int* __restrict__ tab,
                                                u16* __restrict__ MBt) {
#pragma clang fp contract(off)
    __shared__ float hs[128][129];
    int c0g = blockIdx.x * 8;
    int b = (c0g >= 8256) ? 1 : 0;
    const float* hb = hT + b * 16384;
    for (int idx = threadIdx.x; idx < 16384; idx += 256)
        hs[idx >> 7][idx & 127] = hb[idx];
    __syncthreads();
    int n = threadIdx.x & 31, cb = threadIdx.x >> 5;
    for (int cc = 0; cc < 8; ++cc) {
        int colg = c0g + cc;
        int cell = colg - b * 8256;
        int dm = tab[cell];
        int d = dm >> 8, m = dm & 255;
        double xm = m - (d + 1) * 0.5;
        double step = (2 * d + 1) / 95.0;
        float tw[6]; int tt[6];
#pragma unroll
        for (int j = 0; j < 3; ++j) {
            double p = step * (double)(3 * n + j);
            double s = xm + p;
            double tr = trunc(s);
            double dec = s - tr;
            int dn = (int)tr;
            int up = (int)ceil(s);
            bool vdn = (dn >= 0 && dn <= 127);
            bool vup = (up >= 0 && up <= 127);
            tt[2 * j]     = vdn ? dn : 0;
            tw[2 * j]     = vdn ? (float)((1.0 - dec) * (1.0 / 3.0)) : 0.f;
            tt[2 * j + 1] = vup ? up : 0;
            tw[2 * j + 1] = vup ? (float)(dec * (1.0 / 3.0)) : 0.f;
        }
        u16 vals[16];
#pragma unroll
        for (int k = 0; k < 16; ++k) {
            int c = cb + (k << 3);
            float v = 0.f;
#pragma unroll
            for (int i = 0; i < 6; ++i) v = fmaf(tw[i], hs[tt[i]][c], v);
            vals[k] = f2h(v);
        }
        size_t base = (size_t)colg * 4096;
#pragma unroll
        for (int k = 0; k < 16; ++k)
            MBt[base + threadIdx.x + (k << 8)] = vals[k];
    }
}

// ---------------- fused mega-GEMM v4: dbuf A+B, counted-vmcnt pipeline ----------------
// Grid = 130 (65 panels x 2 batches). BM=512, BN=128, BK=64. 8 waves, wave 64m x 128n.
// LDS 160KB: A dbuf 2x64KB @0, B dbuf 2x16KB @131072. XOR swizzle both sides.
// Pipeline: tile t+1's 10 loads stay in flight across compute(t); per iter
// {compute(cur); s_barrier; stage(t+2->cur); vmcnt(10); s_barrier}. Never vmcnt(0)
// in the steady state (T4). Epilogue reuses lds for m3s and runs gemm2 fused.
__global__ __launch_bounds__(512, 2) void mega_kernel(
        const u16* __restrict__ W3h, const u16* __restrict__ MBt,
        const u16* __restrict__ W2h,
        const float* __restrict__ b3, const float* __restrict__ b2,
        const int* __restrict__ tab, float* __restrict__ out) {
    __shared__ alignas(16) char lds[163840];

    const int tid = threadIdx.x;
    const int lane = tid & 63, wv = tid >> 6;
    const int fr = lane & 15, fq = lane >> 4;
    const int swz = (fr & 7) << 4;

    const int p = blockIdx.x;
    const int b = (p >= 65) ? 1 : 0;
    const int pi = p - 65 * b;
    const int cell0 = pi * 128;
    const int cn = (pi == 64) ? 64 : 128;
    const size_t brow0 = (size_t)b * 8256 + cell0;

    f32x4 acc[4][8] = {};

    auto stage = [&](int buf, int kt) {   // exactly 10 global_load_lds per thread
        char* A = lds + buf * 65536;
        char* B = lds + 131072 + buf * 16384;
#pragma unroll
        for (int i = 0; i < 8; ++i) {     // A: 512 rows x 128B
            int off = i * 8192 + tid * 16;
            int row = off >> 7, colb = off & 127;
            int scol = colb ^ ((row & 7) << 4);
            const u16* ga = W3h + (size_t)row * 4096 + kt + (scol >> 1);
            __builtin_amdgcn_global_load_lds(
                (const __attribute__((address_space(1))) void*)ga,
                (__attribute__((address_space(3))) void*)(A + off), 16, 0, 0);
        }
#pragma unroll
        for (int i = 0; i < 2; ++i) {     // B: 128 rows x 128B
            int off = i * 8192 + tid * 16;
            int row = off >> 7, colb = off & 127;
            int r2 = row < cn ? row : 0;
            int scol = colb ^ ((row & 7) << 4);
            const u16* gb = MBt + (brow0 + r2) * 4096 + kt + (scol >> 1);
            __builtin_amdgcn_global_load_lds(
                (const __attribute__((address_space(1))) void*)gb,
                (__attribute__((address_space(3))) void*)(B + off), 16, 0, 0);
        }
    };

    stage(0, 0);
    stage(1, 64);
    asm volatile("s_waitcnt vmcnt(10)" ::: "memory");   // tile 0 landed
    __builtin_amdgcn_sched_barrier(0);
    __builtin_amdgcn_s_barrier();

    for (int t = 0; t < 64; ++t) {
        const int cur = t & 1;
        const char* A = lds + cur * 65536;
        const char* Bp = lds + 131072 + cur * 16384;
#pragma unroll
        for (int kk = 0; kk < 2; ++kk) {
            const int kb = (kk * 64 + (fq << 4)) ^ swz;
            f16x8 af[4], bfr[8];
#pragma unroll
            for (int mf = 0; mf < 4; ++mf)
                af[mf] = *(const f16x8*)(A + (wv * 64 + mf * 16 + fr) * 128 + kb);
#pragma unroll
            for (int nf = 0; nf < 8; ++nf)
                bfr[nf] = *(const f16x8*)(Bp + (nf * 16 + fr) * 128 + kb);
            __builtin_amdgcn_s_setprio(1);
#pragma unroll
            for (int mf = 0; mf < 4; ++mf)
#pragma unroll
                for (int nf = 0; nf < 8; ++nf)
                    acc[mf][nf] = __builtin_amdgcn_mfma_f32_16x16x32_f16(
                        af[mf], bfr[nf], acc[mf][nf], 0, 0, 0);
            __builtin_amdgcn_s_setprio(0);
        }
        __builtin_amdgcn_s_barrier();          // all waves done reading cur
        if (t < 62) {
            stage(cur, (t + 2) << 6);          // overwrite cur with tile t+2
            asm volatile("s_waitcnt vmcnt(10)" ::: "memory");  // tile t+1 landed
        } else {
            asm volatile("s_waitcnt vmcnt(0)" ::: "memory");
        }
        __builtin_amdgcn_sched_barrier(0);
        __builtin_amdgcn_s_barrier();          // next buffer ready for everyone
    }

    // ---- epilogue 1: m3s[cell][o], pitch 520 fp16 (2-way banks: free)
    u16* m3s = (u16*)lds;
#pragma unroll
    for (int mf = 0; mf < 4; ++mf) {
        int ob = wv * 64 + mf * 16 + (fq << 2);
#pragma unroll
        for (int nf = 0; nf < 8; ++nf) {
            int cell = nf * 16 + fr;
            f32x4 v = acc[mf][nf];
            u64 pw = 0;
#pragma unroll
            for (int r = 0; r < 4; ++r) {
                float z = fmaxf(v[r] + b3[ob + r], 0.f);
                pw |= (u64)f2h(z) << (16 * r);
            }
            *(u64*)(m3s + cell * 520 + ob) = pw;
        }
    }
    __syncthreads();

    // ---- epilogue 2: out = relu(W2 . m3 + b2); wave wv owns o2 rows wv*16..+15
    f32x4 acc2[8] = {};
#pragma unroll
    for (int kk = 0; kk < 16; ++kk) {
        f16x8 a2 = *(const f16x8*)(W2h + (wv * 16 + fr) * 512 + kk * 32 + (fq << 3));
#pragma unroll
        for (int nf = 0; nf < 8; ++nf) {
            f16x8 bfr = *(const f16x8*)(m3s + (nf * 16 + fr) * 520 + kk * 32 + (fq << 3));
            acc2[nf] = __builtin_amdgcn_mfma_f32_16x16x32_f16(a2, bfr, acc2[nf], 0, 0, 0);
        }
    }
#pragma unroll
    for (int nf = 0; nf < 8; ++nf) {
        int cl = nf * 16 + fr;
        if (cl < cn) {
            int dm = tab[cell0 + cl];
            size_t base = ((size_t)b << 21) + (size_t)((dm >> 8) << 7) + (dm & 255);
            f32x4 v = acc2[nf];
#pragma unroll
            for (int r = 0; r < 4; ++r) {
                int o2 = wv * 16 + (fq << 2) + r;
                float z = fmaxf(v[r] + b2[o2], 0.f);
                out[base + ((size_t)o2 << 14)] = z;
            }
        }
    }
}

// ws layout (bytes):
//   0        hT      fp32 [2][128][128]            131072
//   131072   W3h     fp16 [512][4096]              4194304
//   4325376  W2h     fp16 [128][512]               131072
//   4456448  c0      fp32 [128]                    512
//   4456960  tab     int  [8256] (alloc 16512)     66048
//   21562368 MBt     fp16 [16512][4096]            135266304
extern "C" void kernel_launch(void* const* d_in, const int* in_sizes, int n_in,
                              void* d_out, int out_size, void* d_ws, size_t ws_size,
                              hipStream_t stream) {
    const float* x     = (const float*)d_in[0];
    const float* w_red = (const float*)d_in[1];
    const float* b_red = (const float*)d_in[2];
    const float* w3d   = (const float*)d_in[3];
    const float* b3d   = (const float*)d_in[4];
    const float* w2d   = (const float*)d_in[5];
    const float* b2d   = (const float*)d_in[6];
    float* out = (float*)d_out;

    char* ws = (char*)d_ws;
    float* hT  = (float*)(ws + 0);
    u16*   W3h = (u16*)(ws + 131072);
    u16*   W2h = (u16*)(ws + 4325376);
    float* c0  = (float*)(ws + 4456448);
    int*   tab = (int*)(ws + 4456960);
    u16*   MBt = (u16*)(ws + 21562368);

    conv_kernel<<<dim3(128, 2), 128, 0, stream>>>(x, w_red, b_red, hT);
    prep_kernel<<<258, 256, 0, stream>>>(w2d, b3d, b2d, tab, W2h, c0);
    cvt_kernel<<<8192, 256, 0, stream>>>(w3d, W3h, 2097152);
    mb_build<<<2064, 256, 0, stream>>>(hT, tab, MBt);
    mega_kernel<<<130, 512, 0, stream>>>(W3h, MBt, W2h, b3d, b2d, tab, out);
    fill_kernel<<<dim3(128, 2), 256, 0, stream>>>(c0, out);
}

// Round 8
// 282.568 us; speedup vs baseline: 1.2602x; 1.0252x over previous
//
#include <hip/hip_runtime.h>

typedef unsigned short u16;
typedef unsigned int u32;
typedef unsigned long long u64;
typedef _Float16 f16x8 __attribute__((ext_vector_type(8)));
typedef float f32x4 __attribute__((ext_vector_type(4)));

__device__ __forceinline__ u16 f2h(float f) {
    _Float16 h = (_Float16)f;
    return __builtin_bit_cast(u16, h);
}

// ---------------- conv1d(256->128,k=3,pad=1)+ReLU -> hT[b][t][c] fp32 ----------------
__global__ void conv_kernel(const float* __restrict__ x, const float* __restrict__ w,
                            const float* __restrict__ bias, float* __restrict__ hT) {
    int co = blockIdx.x, b = blockIdx.y, t = threadIdx.x;  // 128 threads
    float acc = bias[co];
    const float* xb = x + b * 256 * 128;
    const float* wr = w + co * 768;
    for (int ci = 0; ci < 256; ++ci) {
        float w0 = wr[ci * 3 + 0], w1 = wr[ci * 3 + 1], w2 = wr[ci * 3 + 2];
        float x1 = xb[ci * 128 + t];
        float x0 = (t >= 1)   ? xb[ci * 128 + t - 1] : 0.f;
        float x2 = (t < 127) ? xb[ci * 128 + t + 1] : 0.f;
        acc += x0 * w0 + x1 * w1 + x2 * w2;
    }
    hT[b * 16384 + t * 128 + co] = fmaxf(acc, 0.f);
}

// ---------------- prep: 0..255 cvt W2; 256: tab; 257: c0 ----------------
__global__ void prep_kernel(const float* __restrict__ w2d, const float* __restrict__ b3,
                            const float* __restrict__ b2, int* __restrict__ tab,
                            u16* __restrict__ W2h, float* __restrict__ c0) {
    if (blockIdx.x < 256) {
        int i = blockIdx.x * 256 + threadIdx.x;
        W2h[i] = f2h(w2d[i]);
        return;
    }
    if (blockIdx.x == 256) {
        for (int cell = threadIdx.x; cell < 8256; cell += 256) {
            int off = 0, d = 0;
            while (d < 128) { int w = 128 - d; if (cell < off + w) break; off += w; ++d; }
            tab[cell] = (d << 8) | (cell - off);
        }
        return;
    }
    int o2 = threadIdx.x >> 1, half = threadIdx.x & 1;
    float s = 0.f;
    const float* row = w2d + o2 * 512 + half * 256;
    for (int o = 0; o < 256; ++o) s += row[o] * fmaxf(b3[half * 256 + o], 0.f);
    s += __shfl_xor(s, 1);
    if (half == 0) c0[o2] = fmaxf(s + b2[o2], 0.f);
}

// ---------------- fp32 -> fp16 convert (W3) ----------------
__global__ void cvt_kernel(const float* __restrict__ src, u16* __restrict__ dst, int n) {
    int i = blockIdx.x * blockDim.x + threadIdx.x;
    if (i < n) dst[i] = f2h(src[i]);
}

// ---------------- fill invalid cells with c0 ----------------
__global__ void fill_kernel(const float* __restrict__ c0, float* __restrict__ out) {
    int d = blockIdx.x, b = blockIdx.y;
    if (d == 0) return;
    int cnt = d, total = 128 * cnt;
    for (int idx = threadIdx.x; idx < total; idx += blockDim.x) {
        int o2 = idx / cnt, m = 128 - cnt + (idx % cnt);
        out[((size_t)b << 21) + ((size_t)o2 << 14) + (d << 7) + m] = c0[o2];
    }
}

// ---------------- build MBt[(b,cell)][(c,n)] fp16 (bit-exact taps; contract off) --------
// v2: paired layout hs2[t][cp][2] = h[t][cp], h[t][cp+64] -> one float2 LDS read feeds
// two c-channels (48 b64 reads/col instead of 96 b32). Row pitch 130 dwords (!=0 mod 32).
__global__ __launch_bounds__(256) void mb_build(const float* __restrict__ hT,
                                                const int* __restrict__ tab,
                                                u16* __restrict__ MBt) {
#pragma clang fp contract(off)
    __shared__ float hs2[128][65][2];
    int c0g = blockIdx.x * 8;
    int b = (c0g >= 8256) ? 1 : 0;
    const float* hb = hT + b * 16384;
    for (int idx = threadIdx.x; idx < 16384; idx += 256) {
        int t = idx >> 7, c = idx & 127;
        hs2[t][c & 63][c >> 6] = hb[idx];
    }
    __syncthreads();
    int n = threadIdx.x & 31, cb = threadIdx.x >> 5;
    for (int cc = 0; cc < 8; ++cc) {
        int colg = c0g + cc;
        int cell = colg - b * 8256;
        int dm = tab[cell];
        int d = dm >> 8, m = dm & 255;
        double xm = m - (d + 1) * 0.5;
        double step = (2 * d + 1) / 95.0;
        float tw[6]; int tt[6];
#pragma unroll
        for (int j = 0; j < 3; ++j) {
            double p = step * (double)(3 * n + j);   // two roundings, matches numpy
            double s = xm + p;
            double tr = trunc(s);
            double dec = s - tr;
            int dn = (int)tr;
            int up = (int)ceil(s);
            bool vdn = (dn >= 0 && dn <= 127);
            bool vup = (up >= 0 && up <= 127);
            tt[2 * j]     = vdn ? dn : 0;
            tw[2 * j]     = vdn ? (float)((1.0 - dec) * (1.0 / 3.0)) : 0.f;
            tt[2 * j + 1] = vup ? up : 0;
            tw[2 * j + 1] = vup ? (float)(dec * (1.0 / 3.0)) : 0.f;
        }
        u16 vals[16];
#pragma unroll
        for (int k = 0; k < 8; ++k) {
            int cp = cb + (k << 3);
            float v0 = 0.f, v1 = 0.f;
#pragma unroll
            for (int i = 0; i < 6; ++i) {
                float2 hv = *(const float2*)&hs2[tt[i]][cp][0];
                v0 = fmaf(tw[i], hv.x, v0);
                v1 = fmaf(tw[i], hv.y, v1);
            }
            vals[k] = f2h(v0);
            vals[k + 8] = f2h(v1);
        }
        size_t base = (size_t)colg * 4096;
#pragma unroll
        for (int k = 0; k < 16; ++k)
            MBt[base + threadIdx.x + (k << 8)] = vals[k];
    }
}

// ---------------- GEMM1: m3T[row=bcell][512 o] = relu(W3h . MBt^T + b3) ----------------
// BM=128 (o-split s=0..3), BN=128 cells, BK=64. 256 thr, 4 waves, wave-tile 64x64,
// acc[4][4]=64 VGPR, LDS 64KB -> 2 blocks/CU co-resident (cross-block overlap).
// Grid 520 = 130 panels x 4 o-splits; quad-XCD remap co-locates a panel's 4 splits.
// Counted vmcnt(8) pipeline, XOR swizzle both sides.
__global__ __launch_bounds__(256, 2) void mega_kernel(
        const u16* __restrict__ W3h, const u16* __restrict__ MBt,
        const float* __restrict__ b3, u16* __restrict__ m3T) {
    __shared__ alignas(16) char lds[65536];

    const int tid = threadIdx.x;
    const int lane = tid & 63, wv = tid >> 6;
    const int fr = lane & 15, fq = lane >> 4;
    const int swz = (fr & 7) << 4;
    const int wm = wv >> 1, wn = wv & 1;           // 2m x 2n wave grid

    // blockIdx -> (panel quad q, split s): splits of one panel share i%8 (same XCD)
    int i = blockIdx.x, q, s;
    if (i < 512) { int c = i >> 5, r = i & 31; s = r >> 3; q = c * 8 + (r & 7); }
    else         { int t2 = i - 512; q = 128 + (t2 >> 2); s = t2 & 3; }
    const int b = (q >= 65) ? 1 : 0;
    const int pi = q - 65 * b;
    const int cell0 = pi * 128;
    const int cn = (pi == 64) ? 64 : 128;
    const size_t brow0 = (size_t)b * 8256 + cell0;
    const int m0 = s * 128;

    f32x4 acc[4][4] = {};

    auto stage = [&](int buf, int kt) {            // 8 global_load_lds per thread
        char* A = lds + buf * 16384;
        char* B = lds + 32768 + buf * 16384;
#pragma unroll
        for (int i2 = 0; i2 < 4; ++i2) {           // A: 128 rows x 128B
            int off = i2 * 4096 + tid * 16;
            int row = off >> 7, colb = off & 127;
            int scol = colb ^ ((row & 7) << 4);
            const u16* ga = W3h + (size_t)(m0 + row) * 4096 + kt + (scol >> 1);
            __builtin_amdgcn_global_load_lds(
                (const __attribute__((address_space(1))) void*)ga,
                (__attribute__((address_space(3))) void*)(A + off), 16, 0, 0);
        }
#pragma unroll
        for (int i2 = 0; i2 < 4; ++i2) {           // B: 128 rows x 128B
            int off = i2 * 4096 + tid * 16;
            int row = off >> 7, colb = off & 127;
            int r2 = row < cn ? row : 0;
            int scol = colb ^ ((row & 7) << 4);
            const u16* gb = MBt + (brow0 + r2) * 4096 + kt + (scol >> 1);
            __builtin_amdgcn_global_load_lds(
                (const __attribute__((address_space(1))) void*)gb,
                (__attribute__((address_space(3))) void*)(B + off), 16, 0, 0);
        }
    };

    stage(0, 0);
    stage(1, 64);
    asm volatile("s_waitcnt vmcnt(8)" ::: "memory");   // tile 0 landed
    __builtin_amdgcn_sched_barrier(0);
    __builtin_amdgcn_s_barrier();
    __builtin_amdgcn_sched_barrier(0);

    for (int t = 0; t < 64; ++t) {
        const int cur = t & 1;
        const char* A = lds + cur * 16384;
        const char* Bp = lds + 32768 + cur * 16384;
#pragma unroll
        for (int kk = 0; kk < 2; ++kk) {
            const int kb = (kk * 64 + (fq << 4)) ^ swz;
            f16x8 af[4], bfr[4];
#pragma unroll
            for (int mf = 0; mf < 4; ++mf)
                af[mf] = *(const f16x8*)(A + (wm * 64 + mf * 16 + fr) * 128 + kb);
#pragma unroll
            for (int nf = 0; nf < 4; ++nf)
                bfr[nf] = *(const f16x8*)(Bp + (wn * 64 + nf * 16 + fr) * 128 + kb);
            __builtin_amdgcn_s_setprio(1);
#pragma unroll
            for (int mf = 0; mf < 4; ++mf)
#pragma unroll
                for (int nf = 0; nf < 4; ++nf)
                    acc[mf][nf] = __builtin_amdgcn_mfma_f32_16x16x32_f16(
                        af[mf], bfr[nf], acc[mf][nf], 0, 0, 0);
            __builtin_amdgcn_s_setprio(0);
        }
        __builtin_amdgcn_s_barrier();              // all waves done reading cur
        if (t < 62) {
            stage(cur, (t + 2) << 6);
            asm volatile("s_waitcnt vmcnt(8)" ::: "memory");   // tile t+1 landed
        } else {
            asm volatile("s_waitcnt vmcnt(0)" ::: "memory");
        }
        __builtin_amdgcn_sched_barrier(0);
        __builtin_amdgcn_s_barrier();
        __builtin_amdgcn_sched_barrier(0);
    }

    // epilogue: m3T[brow0+cl][o] = fp16(relu(acc + b3[o]))
#pragma unroll
    for (int mf = 0; mf < 4; ++mf) {
        int o = m0 + wm * 64 + mf * 16 + (fq << 2);
#pragma unroll
        for (int nf = 0; nf < 4; ++nf) {
            int cl = wn * 64 + nf * 16 + fr;
            if (cl < cn) {
                f32x4 v = acc[mf][nf];
                u64 pw = 0;
#pragma unroll
                for (int r = 0; r < 4; ++r) {
                    float z = fmaxf(v[r] + b3[o + r], 0.f);
                    pw |= (u64)f2h(z) << (16 * r);
                }
                *(u64*)(m3T + (brow0 + cl) * 512 + o) = pw;
            }
        }
    }
}

// ---------------- GEMM2: out = relu(W2 . m3 + b2), scatter via tab ----------------
// A = m3T[16512][512], B = W2h[128][512]. 129 blocks x 128 cells. (R3-proven body.)
__global__ __launch_bounds__(256) void gemm2_kernel(const u16* __restrict__ A,
                                                    const u16* __restrict__ B,
                                                    const float* __restrict__ bias,
                                                    const int* __restrict__ tab,
                                                    float* __restrict__ out) {
    __shared__ alignas(16) u16 As[128 * 64];
    __shared__ alignas(16) u16 Bs[128 * 64];
    const int tid = threadIdx.x;
    const int lane = tid & 63, wave = tid >> 6;
    const int m0 = blockIdx.x * 128;
    const int wr = wave & 1, wc = wave >> 1;
    const int fr = lane & 15, fk = (lane >> 4) * 16;
    f32x4 acc[4][4] = {};

    for (int kt = 0; kt < 512; kt += 64) {
#pragma unroll
        for (int i = 0; i < 4; ++i) {
            int off = i * 4096 + wave * 1024 + lane * 16;
            int row = off >> 7, colb = off & 127;
            const u16* ga = A + (size_t)(m0 + row) * 512 + kt + (colb >> 1);
            const u16* gb = B + (size_t)row * 512 + kt + (colb >> 1);
            __builtin_amdgcn_global_load_lds(
                (const __attribute__((address_space(1))) void*)ga,
                (__attribute__((address_space(3))) void*)((char*)As + i * 4096 + wave * 1024),
                16, 0, 0);
            __builtin_amdgcn_global_load_lds(
                (const __attribute__((address_space(1))) void*)gb,
                (__attribute__((address_space(3))) void*)((char*)Bs + i * 4096 + wave * 1024),
                16, 0, 0);
        }
        __syncthreads();
#pragma unroll
        for (int kk = 0; kk < 2; ++kk) {
            f16x8 af[4], bfr[4];
            const int kb = kk * 64 + fk;
#pragma unroll
            for (int mf = 0; mf < 4; ++mf)
                af[mf] = *(const f16x8*)((const char*)As + (wr * 64 + mf * 16 + fr) * 128 + kb);
#pragma unroll
            for (int nf = 0; nf < 4; ++nf)
                bfr[nf] = *(const f16x8*)((const char*)Bs + (wc * 64 + nf * 16 + fr) * 128 + kb);
#pragma unroll
            for (int mf = 0; mf < 4; ++mf)
#pragma unroll
                for (int nf = 0; nf < 4; ++nf)
                    acc[mf][nf] = __builtin_amdgcn_mfma_f32_16x16x32_f16(
                        af[mf], bfr[nf], acc[mf][nf], 0, 0, 0);
        }
        __syncthreads();
    }

#pragma unroll
    for (int mf = 0; mf < 4; ++mf) {
        int rbase = m0 + wr * 64 + mf * 16 + ((lane >> 4) << 2);
#pragma unroll
        for (int nf = 0; nf < 4; ++nf) {
            int o2 = wc * 64 + nf * 16 + fr;
            f32x4 v = acc[mf][nf];
#pragma unroll
            for (int r = 0; r < 4; ++r) {
                int colg = rbase + r;
                int b = (colg >= 8256) ? 1 : 0;
                int cell = colg - b * 8256;
                int dm = tab[cell];
                float z = fmaxf(v[r] + bias[o2], 0.f);
                out[((size_t)b << 21) + ((size_t)o2 << 14) + ((dm >> 8) << 7) + (dm & 255)] = z;
            }
        }
    }
}

// ws layout (bytes):
//   0        hT      fp32 [2][128][128]            131072
//   131072   W3h     fp16 [512][4096]              4194304
//   4325376  W2h     fp16 [128][512]               131072
//   4456448  c0      fp32 [128]                    512
//   4456960  tab     int  [8256] (alloc 16512)     66048
//   4523008  m3T     fp16 [16512][512]             16908288
//   21562368 MBt     fp16 [16512][4096]            135266304
extern "C" void kernel_launch(void* const* d_in, const int* in_sizes, int n_in,
                              void* d_out, int out_size, void* d_ws, size_t ws_size,
                              hipStream_t stream) {
    const float* x     = (const float*)d_in[0];
    const float* w_red = (const float*)d_in[1];
    const float* b_red = (const float*)d_in[2];
    const float* w3d   = (const float*)d_in[3];
    const float* b3d   = (const float*)d_in[4];
    const float* w2d   = (const float*)d_in[5];
    const float* b2d   = (const float*)d_in[6];
    float* out = (float*)d_out;

    char* ws = (char*)d_ws;
    float* hT  = (float*)(ws + 0);
    u16*   W3h = (u16*)(ws + 131072);
    u16*   W2h = (u16*)(ws + 4325376);
    float* c0  = (float*)(ws + 4456448);
    int*   tab = (int*)(ws + 4456960);
    u16*   m3T = (u16*)(ws + 4523008);
    u16*   MBt = (u16*)(ws + 21562368);

    conv_kernel<<<dim3(128, 2), 128, 0, stream>>>(x, w_red, b_red, hT);
    prep_kernel<<<258, 256, 0, stream>>>(w2d, b3d, b2d, tab, W2h, c0);
    cvt_kernel<<<8192, 256, 0, stream>>>(w3d, W3h, 2097152);
    mb_build<<<2064, 256, 0, stream>>>(hT, tab, MBt);
    mega_kernel<<<520, 256, 0, stream>>>(W3h, MBt, b3d, m3T);
    gemm2_kernel<<<129, 256, 0, stream>>>(m3T, W2h, b2d, tab, out);
    fill_kernel<<<dim3(128, 2), 256, 0, stream>>>(c0, out);
}